// Round 23
// baseline (95.045 us; speedup 1.0000x reference)
//
#include <hip/hip_runtime.h>
#include <hip/hip_bf16.h>

typedef __bf16 bf16x8 __attribute__((ext_vector_type(8)));
typedef __bf16 bf16x4 __attribute__((ext_vector_type(4)));
typedef float f32x4 __attribute__((ext_vector_type(4)));

#define MFMA16(a, b, c) __builtin_amdgcn_mfma_f32_16x16x32_bf16((a), (b), (c), 0, 0, 0)

constexpr int kB = 4096, kN = 49, kC = 128;
constexpr float kScale = 0.17677669529663687f;   // 32^-0.5
constexpr float kLog2e = 1.4426950408889634f;
constexpr float kQScale = kScale * kLog2e;       // folded into Wq + q-bias

// workspace layout (bytes)
constexpr size_t WQ_OFF = 0;        // qkv_w packed bf16: [24][4][64][8] = 98304 B
constexpr size_t WP_OFF = 98304;    // proj_w packed bf16: [8][4][64][8] = 32768 B
constexpr size_t BP_OFF = 131072;   // bias f32 [4][64 tok][64 key] *log2e, -inf at key>=49
constexpr size_t MF_OFF = 196608;   // mask-nonzero flags: 8 ints

// ---------------------------------------------------------------------------
// prep: pack weights bf16 fragment-linear. Q/K tiles: PERMUTED dim order so
// MFMA C-layout == frag layout (lane-local, zero shuffles). proj tiles:
// n-INTERLEAVED column pairs (lane lm -> natural cols w*32+2lm+{0,1}) so the
// epilogue writes full 128B lines via float2.
// ---------------------------------------------------------------------------
__global__ void prep_kernel(const float* __restrict__ qkv_w,
                            const float* __restrict__ proj_w,
                            const float* __restrict__ bias_table,
                            const int* __restrict__ rel_raw,
                            const float* __restrict__ maskp,
                            __bf16* __restrict__ wq, __bf16* __restrict__ wp,
                            float* __restrict__ biasp, int* __restrict__ mf) {
  const int blk = blockIdx.x, t = threadIdx.x;
  // int64-vs-int32 sniff: rel[0]=84 -> int64 word1 is 0; int32 word1 = 83
  const bool is64 = (rel_raw[1] == 0);
  if (blk < 16) {  // Q/K tiles, permuted dim order
    const int kk = t >> 6, lane = t & 63, lm = lane & 15;
    const int k0 = kk * 32 + ((lane >> 4) << 3);
    const int qk = blk >> 3, head = (blk >> 1) & 3, dt = blk & 1;
    const int c = qk * 128 + head * 32 + ((lm >> 2) << 3) + dt * 4 + (lm & 3);
    const float s = (qk == 0) ? kQScale : 1.f;
#pragma unroll
    for (int i = 0; i < 8; ++i)
      wq[((blk * 4 + kk) * 64 + lane) * 8 + i] =
          (__bf16)(qkv_w[(k0 + i) * 384 + c] * s);
  } else if (blk < 24) {  // V tiles, natural order
    const int kk = t >> 6, lane = t & 63;
    const int k0 = kk * 32 + ((lane >> 4) << 3);
    const int c  = blk * 16 + (lane & 15);
#pragma unroll
    for (int i = 0; i < 8; ++i)
      wq[((blk * 4 + kk) * 64 + lane) * 8 + i] = (__bf16)qkv_w[(k0 + i) * 384 + c];
  } else if (blk < 32) {  // proj_w pack, n-interleaved column pairs
    const int nt = blk - 24;           // nt = w*2 + n
    const int kk = t >> 6, lane = t & 63, lm = lane & 15;
    const int k0 = kk * 32 + ((lane >> 4) << 3);
    const int c = (nt >> 1) * 32 + 2 * lm + (nt & 1);
#pragma unroll
    for (int i = 0; i < 8; ++i)
      wp[((nt * 4 + kk) * 64 + lane) * 8 + i] = (__bf16)proj_w[(k0 + i) * 128 + c];
  } else if (blk < 96) {  // biasp [h][tok64][key64] * log2e, key>=49 -> -1e30
    const int e = (blk - 32) * 256 + t;
    const int h = e >> 12, tok = (e >> 6) & 63, key = e & 63;
    float v;
    if (key >= kN) v = -1e30f;
    else if (tok >= kN) v = 0.f;
    else {
      const int flat = tok * kN + key;
      const int idx = is64 ? rel_raw[2 * flat] : rel_raw[flat];
      v = bias_table[idx * 4 + h] * kLog2e;
    }
    biasp[(h * 64 + tok) * 64 + key] = v;
  } else {  // blk 96..103: mask nonzero flag (64*49*49 = 153664 elems)
    const int base = (blk - 96) * 19208;
    int any = 0;
    for (int e = base + t; e < base + 19208; e += 256)
      any |= (__float_as_uint(maskp[e]) != 0u) ? 1 : 0;
    const int blkany = __syncthreads_or(any);
    if (t == 0) mf[blk - 96] = blkany;
  }
}

__device__ __forceinline__ uint2 pack4(f32x4 v) {
  bf16x4 h;
  h[0] = (__bf16)v[0]; h[1] = (__bf16)v[1]; h[2] = (__bf16)v[2]; h[3] = (__bf16)v[3];
  return *(uint2*)&h;
}

// concat two uint2 (4 bf16 each) into one bf16x8 frag: i = dt*4 + j
__device__ __forceinline__ bf16x8 cat2(uint2 a, uint2 b) {
  uint4 u;
  u.x = a.x; u.y = a.y; u.z = b.x; u.w = b.y;
  return *(bf16x8*)&u;
}

// ---------------------------------------------------------------------------
// fused window attention: 1 block = 1 window, 4 waves = 4 heads.
// x staged once in LDS; SEPARATE ob buffer (34.8 KB), 2 barriers.
// PV computed TRANSPOSED via operand swap (one bf16x4 LDS write per (tt,dt)).
// bounds(256,3): 170-reg budget (R20: occupancy-insensitive 28-38%).
// ALL QKV weights prefetched before staging; proj weights prefetched before
// the attention loop; attn-bias loads DOUBLE-BUFFERED across the tt loop
// (R18 mechanism, unblocked by the relaxed register budget).
// ---------------------------------------------------------------------------
__global__ __launch_bounds__(256, 3)
void wattn_fused(const float* __restrict__ x, const float* __restrict__ qkv_b,
                 const float* __restrict__ proj_b,
                 const __bf16* __restrict__ wq, const __bf16* __restrict__ wp,
                 const float* __restrict__ biasp, const float* __restrict__ mask,
                 const int* __restrict__ mf, float* __restrict__ out) {
  constexpr int XS = 136, OBS = 136;
  __shared__ __align__(16) __bf16 xb[64 * XS];  // 17408 B
  __shared__ __align__(16) __bf16 ob[64 * OBS]; // 17408 B (separate buffer)

  const int tid = threadIdx.x;
  const int w = tid >> 6, lane = tid & 63, lg = lane >> 4, lm = lane & 15;
  const int b = blockIdx.x;
  const f32x4 zero4 = {0.f, 0.f, 0.f, 0.f};

  const bool hasMask =
      (mf[0] | mf[1] | mf[2] | mf[3] | mf[4] | mf[5] | mf[6] | mf[7]) != 0;

  // ---- hoist ALL QKV weights + biases (latency hides under staging/B1) ----
  bf16x8 wfq[2][4], wfk[2][4], wfv[2][4];
  f32x4 qb4[2], kb4[2];
  float vb[2];
#pragma unroll
  for (int dt = 0; dt < 2; ++dt) {
#pragma unroll
    for (int kk = 0; kk < 4; ++kk) {
      wfq[dt][kk] = *(const bf16x8*)(wq + ((size_t)(((2 * w + dt)) * 4 + kk) * 64 + lane) * 8);
      wfk[dt][kk] = *(const bf16x8*)(wq + ((size_t)((8 + 2 * w + dt) * 4 + kk) * 64 + lane) * 8);
      wfv[dt][kk] = *(const bf16x8*)(wq + ((size_t)((16 + 2 * w + dt) * 4 + kk) * 64 + lane) * 8);
    }
    qb4[dt] = *(const f32x4*)(qkv_b + w * 32 + lg * 8 + dt * 4);
#pragma unroll
    for (int j = 0; j < 4; ++j) qb4[dt][j] *= kQScale;
    kb4[dt] = *(const f32x4*)(qkv_b + 128 + w * 32 + lg * 8 + dt * 4);
    vb[dt]  = qkv_b[256 + w * 32 + dt * 16 + lm];
  }

  // ---- stage x -> xb bf16 (rows 49-63 = row 48 replica) ----
  {
    const float* xp = x + (size_t)b * (kN * kC);
#pragma unroll
    for (int i = 0; i < 8; ++i) {
      const int it = tid + i * 256;
      const int row = it >> 5, col = (it & 31) << 2;
      const int sr = row < kN ? row : (kN - 1);
      f32x4 v = *(const f32x4*)(xp + sr * kC + col);
      bf16x4 h;
      h[0] = (__bf16)v[0]; h[1] = (__bf16)v[1]; h[2] = (__bf16)v[2]; h[3] = (__bf16)v[3];
      *(bf16x4*)(xb + row * XS + col) = h;
    }
  }
  __syncthreads();  // B1: xb ready

#define LDAF(tt, kk) (*(const bf16x8*)(xb + ((tt) * 16 + lm) * XS + (kk) * 32 + lg * 8))

  bf16x8 qf[4], kf[4], vf[2][2];

  // ---- Q^T (permuted dims, dt-outer; bias = acc init; weights resident) ----
  {
    uint2 qh[4][2];
#pragma unroll
    for (int dt = 0; dt < 2; ++dt) {
#pragma unroll
      for (int tt = 0; tt < 4; ++tt) {
        f32x4 acc = qb4[dt];
        __builtin_amdgcn_s_setprio(1);
#pragma unroll
        for (int kk = 0; kk < 4; ++kk) acc = MFMA16(wfq[dt][kk], LDAF(tt, kk), acc);
        __builtin_amdgcn_s_setprio(0);
        qh[tt][dt] = pack4(acc);
      }
    }
#pragma unroll
    for (int tt = 0; tt < 4; ++tt) qf[tt] = cat2(qh[tt][0], qh[tt][1]);
  }

  // ---- K^T (permuted dims, dt-outer; bias = acc init; weights resident) ----
  {
    uint2 kh[4][2];
#pragma unroll
    for (int dt = 0; dt < 2; ++dt) {
#pragma unroll
      for (int tt = 0; tt < 4; ++tt) {
        f32x4 acc = kb4[dt];
        __builtin_amdgcn_s_setprio(1);
#pragma unroll
        for (int kk = 0; kk < 4; ++kk) acc = MFMA16(wfk[dt][kk], LDAF(tt, kk), acc);
        __builtin_amdgcn_s_setprio(0);
        kh[tt][dt] = pack4(acc);
      }
    }
#pragma unroll
    for (int kt = 0; kt < 4; ++kt) kf[kt] = cat2(kh[kt][0], kh[kt][1]);
  }

  // ---- V = x Wv (natural order, dt-outer; bias = acc init; weights resident) ----
  {
    uint2 vh[4][2];
#pragma unroll
    for (int dt = 0; dt < 2; ++dt) {
#pragma unroll
      for (int mt = 0; mt < 4; ++mt) {
        f32x4 acc = {vb[dt], vb[dt], vb[dt], vb[dt]};
        __builtin_amdgcn_s_setprio(1);
#pragma unroll
        for (int kk = 0; kk < 4; ++kk) acc = MFMA16(LDAF(mt, kk), wfv[dt][kk], acc);
        __builtin_amdgcn_s_setprio(0);
        vh[mt][dt] = pack4(acc);
      }
    }
#pragma unroll
    for (int ks = 0; ks < 2; ++ks)
#pragma unroll
      for (int dt = 0; dt < 2; ++dt)
        vf[ks][dt] = cat2(vh[ks * 2][dt], vh[ks * 2 + 1][dt]);
  }
  // no barrier: ob is a separate buffer

  // ---- hoist proj weights + bias: attention covers their latency ----
  bf16x8 wpb[2][4];
#pragma unroll
  for (int n = 0; n < 2; ++n)
#pragma unroll
    for (int kk = 0; kk < 4; ++kk)
      wpb[n][kk] = *(const bf16x8*)(wp + (size_t)(((w * 2 + n) * 4 + kk) * 64 + lane) * 8);
  const float pb0 = proj_b[w * 32 + 2 * lm];
  const float pb1 = proj_b[w * 32 + 2 * lm + 1];

  // ---- attention: S^T = K·Q^T (+bias incl. key mask), exp2 softmax, PV^T ----
  const float* bpp = biasp + w * 4096;
  const float* mkp = mask + (size_t)(b & 63) * (kN * kN);

  // bias double-buffer: tt=0 loads issued ahead of the loop
  f32x4 bm[4];
#pragma unroll
  for (int kt = 0; kt < 4; ++kt)
    bm[kt] = *(const f32x4*)(bpp + (lm << 6) + kt * 16 + lg * 4);

#pragma unroll
  for (int tt = 0; tt < 4; ++tt) {
    const int tok = tt * 16 + lm;
    f32x4 st[4];
    __builtin_amdgcn_s_setprio(1);
#pragma unroll
    for (int kt = 0; kt < 4; ++kt) st[kt] = MFMA16(kf[kt], qf[tt], zero4);
    __builtin_amdgcn_s_setprio(0);
    // prefetch next tile's bias; consumed next iteration (~full tile of cover)
    f32x4 bmn[4];
    if (tt < 3) {
#pragma unroll
      for (int kt = 0; kt < 4; ++kt)
        bmn[kt] = *(const f32x4*)(bpp + ((tok + 16) << 6) + kt * 16 + lg * 4);
    }
#pragma unroll
    for (int kt = 0; kt < 4; ++kt)
#pragma unroll
      for (int j = 0; j < 4; ++j) st[kt][j] += bm[kt][j];
    if (hasMask) {
      const int tok2 = tok < kN ? tok : (kN - 1);
#pragma unroll
      for (int kt = 0; kt < 4; ++kt)
#pragma unroll
        for (int j = 0; j < 4; ++j) {
          const int key = kt * 16 + lg * 4 + j;
          const int key2 = key < kN ? key : (kN - 1);
          st[kt][j] += mkp[tok2 * kN + key2] * kLog2e;
        }
    }
    // softmax over keys in exp2 domain (keys on (kt,lg,j); token on lm)
    float m = -3e38f;
#pragma unroll
    for (int kt = 0; kt < 4; ++kt)
#pragma unroll
      for (int j = 0; j < 4; ++j) m = fmaxf(m, st[kt][j]);
    m = fmaxf(m, __shfl_xor(m, 16));
    m = fmaxf(m, __shfl_xor(m, 32));
    float sum = 0.f;
#pragma unroll
    for (int kt = 0; kt < 4; ++kt)
#pragma unroll
      for (int j = 0; j < 4; ++j) {
        const float e = exp2f(st[kt][j] - m);
        st[kt][j] = e;
        sum += e;
      }
    sum += __shfl_xor(sum, 16);
    sum += __shfl_xor(sum, 32);
    const float rs = __builtin_amdgcn_rcpf(sum);
    uint2 pst[4];
#pragma unroll
    for (int kt = 0; kt < 4; ++kt) {
      f32x4 t;
#pragma unroll
      for (int j = 0; j < 4; ++j) t[j] = st[kt][j] * rs;
      pst[kt] = pack4(t);
    }
    // bit-shuffled key order: pa/vf agree -> pure lane-local assembly
    bf16x8 pa0 = cat2(pst[0], pst[1]);
    bf16x8 pa1 = cat2(pst[2], pst[3]);
    // PV TRANSPOSED: mfma(vf, pa) = V^T·P^T = O^T[dim][tok]; lane lm = tok,
    // rows lg*4+j = 4 consecutive dims -> one bf16x4 write per (tt,dt)
#pragma unroll
    for (int dt = 0; dt < 2; ++dt) {
      f32x4 o = MFMA16(vf[0][dt], pa0, zero4);
      o = MFMA16(vf[1][dt], pa1, o);
      bf16x4 ho;
#pragma unroll
      for (int j = 0; j < 4; ++j) ho[j] = (__bf16)o[j];
      *(bf16x4*)(ob + (tt * 16 + lm) * OBS + w * 32 + dt * 16 + lg * 4) = ho;
    }
#pragma unroll
    for (int kt = 0; kt < 4; ++kt) bm[kt] = bmn[kt];
  }

  __syncthreads();  // B2: ob ready

  // ---- proj GEMM: n-interleaved wp -> lane lm owns cols w*32+2lm+{0,1};
  //      float2 stores = full 128B lines per 16-lane group ----
  {
    float* op = out + (size_t)b * (kN * kC);
#pragma unroll
    for (int mt = 0; mt < 4; ++mt) {
      bf16x8 paf[4];
#pragma unroll
      for (int kk = 0; kk < 4; ++kk)
        paf[kk] = *(const bf16x8*)(ob + (mt * 16 + lm) * OBS + kk * 32 + lg * 8);
      f32x4 a0 = zero4, a1 = zero4;
      __builtin_amdgcn_s_setprio(1);
#pragma unroll
      for (int kk = 0; kk < 4; ++kk) {
        a0 = MFMA16(paf[kk], wpb[0][kk], a0);
        a1 = MFMA16(paf[kk], wpb[1][kk], a1);
      }
      __builtin_amdgcn_s_setprio(0);
#pragma unroll
      for (int j = 0; j < 4; ++j) {
        const int r = mt * 16 + lg * 4 + j;
        if (r < kN) {
          float2 st2;
          st2.x = a0[j] + pb0;
          st2.y = a1[j] + pb1;
          *(float2*)(op + r * kC + w * 32 + 2 * lm) = st2;
        }
      }
    }
  }
#undef LDAF
}

// ---------------------------------------------------------------------------
extern "C" void kernel_launch(void* const* d_in, const int* in_sizes, int n_in,
                              void* d_out, int out_size, void* d_ws, size_t ws_size,
                              hipStream_t stream) {
  const float* x          = (const float*)d_in[0];
  const float* mask       = (const float*)d_in[1];
  const float* qkv_w      = (const float*)d_in[2];
  const float* qkv_b      = (const float*)d_in[3];
  const float* proj_w     = (const float*)d_in[4];
  const float* proj_b     = (const float*)d_in[5];
  const float* bias_table = (const float*)d_in[6];
  const int*   rel        = (const int*)d_in[7];

  char* ws = (char*)d_ws;
  __bf16* wq   = (__bf16*)(ws + WQ_OFF);
  __bf16* wp   = (__bf16*)(ws + WP_OFF);
  float* biasp = (float*)(ws + BP_OFF);
  int*   mf    = (int*)(ws + MF_OFF);

  prep_kernel<<<104, 256, 0, stream>>>(qkv_w, proj_w, bias_table, rel, mask,
                                       wq, wp, biasp, mf);
  wattn_fused<<<kB, 256, 0, stream>>>(x, qkv_b, proj_b, wq, wp, biasp, mask,
                                      mf, (float*)d_out);
}

// Round 24
// 87.300 us; speedup vs baseline: 1.0887x; 1.0887x over previous
//
#include <hip/hip_runtime.h>
#include <hip/hip_bf16.h>

typedef __bf16 bf16x8 __attribute__((ext_vector_type(8)));
typedef __bf16 bf16x4 __attribute__((ext_vector_type(4)));
typedef float f32x4 __attribute__((ext_vector_type(4)));

#define MFMA16(a, b, c) __builtin_amdgcn_mfma_f32_16x16x32_bf16((a), (b), (c), 0, 0, 0)

constexpr int kB = 4096, kN = 49, kC = 128;
constexpr float kScale = 0.17677669529663687f;   // 32^-0.5
constexpr float kLog2e = 1.4426950408889634f;
constexpr float kQScale = kScale * kLog2e;       // folded into Wq + q-bias

// workspace layout (bytes)
constexpr size_t WQ_OFF = 0;        // qkv_w packed bf16: [24][4][64][8] = 98304 B
constexpr size_t WP_OFF = 98304;    // proj_w packed bf16: [8][4][64][8] = 32768 B
constexpr size_t BP_OFF = 131072;   // bias f32 [4][64 tok][64 key] *log2e, -inf at key>=49
constexpr size_t MF_OFF = 196608;   // mask-nonzero flags: 8 ints

// ---------------------------------------------------------------------------
// prep: pack weights bf16 fragment-linear. Q/K tiles: PERMUTED dim order so
// MFMA C-layout == frag layout (lane-local, zero shuffles). proj tiles:
// n-INTERLEAVED column pairs (lane lm -> natural cols w*32+2lm+{0,1}) so the
// epilogue writes full 128B lines via float2.
// ---------------------------------------------------------------------------
__global__ void prep_kernel(const float* __restrict__ qkv_w,
                            const float* __restrict__ proj_w,
                            const float* __restrict__ bias_table,
                            const int* __restrict__ rel_raw,
                            const float* __restrict__ maskp,
                            __bf16* __restrict__ wq, __bf16* __restrict__ wp,
                            float* __restrict__ biasp, int* __restrict__ mf) {
  const int blk = blockIdx.x, t = threadIdx.x;
  // int64-vs-int32 sniff: rel[0]=84 -> int64 word1 is 0; int32 word1 = 83
  const bool is64 = (rel_raw[1] == 0);
  if (blk < 16) {  // Q/K tiles, permuted dim order
    const int kk = t >> 6, lane = t & 63, lm = lane & 15;
    const int k0 = kk * 32 + ((lane >> 4) << 3);
    const int qk = blk >> 3, head = (blk >> 1) & 3, dt = blk & 1;
    const int c = qk * 128 + head * 32 + ((lm >> 2) << 3) + dt * 4 + (lm & 3);
    const float s = (qk == 0) ? kQScale : 1.f;
#pragma unroll
    for (int i = 0; i < 8; ++i)
      wq[((blk * 4 + kk) * 64 + lane) * 8 + i] =
          (__bf16)(qkv_w[(k0 + i) * 384 + c] * s);
  } else if (blk < 24) {  // V tiles, natural order
    const int kk = t >> 6, lane = t & 63;
    const int k0 = kk * 32 + ((lane >> 4) << 3);
    const int c  = blk * 16 + (lane & 15);
#pragma unroll
    for (int i = 0; i < 8; ++i)
      wq[((blk * 4 + kk) * 64 + lane) * 8 + i] = (__bf16)qkv_w[(k0 + i) * 384 + c];
  } else if (blk < 32) {  // proj_w pack, n-interleaved column pairs
    const int nt = blk - 24;           // nt = w*2 + n
    const int kk = t >> 6, lane = t & 63, lm = lane & 15;
    const int k0 = kk * 32 + ((lane >> 4) << 3);
    const int c = (nt >> 1) * 32 + 2 * lm + (nt & 1);
#pragma unroll
    for (int i = 0; i < 8; ++i)
      wp[((nt * 4 + kk) * 64 + lane) * 8 + i] = (__bf16)proj_w[(k0 + i) * 128 + c];
  } else if (blk < 96) {  // biasp [h][tok64][key64] * log2e, key>=49 -> -1e30
    const int e = (blk - 32) * 256 + t;
    const int h = e >> 12, tok = (e >> 6) & 63, key = e & 63;
    float v;
    if (key >= kN) v = -1e30f;
    else if (tok >= kN) v = 0.f;
    else {
      const int flat = tok * kN + key;
      const int idx = is64 ? rel_raw[2 * flat] : rel_raw[flat];
      v = bias_table[idx * 4 + h] * kLog2e;
    }
    biasp[(h * 64 + tok) * 64 + key] = v;
  } else {  // blk 96..103: mask nonzero flag (64*49*49 = 153664 elems)
    const int base = (blk - 96) * 19208;
    int any = 0;
    for (int e = base + t; e < base + 19208; e += 256)
      any |= (__float_as_uint(maskp[e]) != 0u) ? 1 : 0;
    const int blkany = __syncthreads_or(any);
    if (t == 0) mf[blk - 96] = blkany;
  }
}

__device__ __forceinline__ uint2 pack4(f32x4 v) {
  bf16x4 h;
  h[0] = (__bf16)v[0]; h[1] = (__bf16)v[1]; h[2] = (__bf16)v[2]; h[3] = (__bf16)v[3];
  return *(uint2*)&h;
}

// concat two uint2 (4 bf16 each) into one bf16x8 frag: i = dt*4 + j
__device__ __forceinline__ bf16x8 cat2(uint2 a, uint2 b) {
  uint4 u;
  u.x = a.x; u.y = a.y; u.z = b.x; u.w = b.y;
  return *(bf16x8*)&u;
}

// ---------------------------------------------------------------------------
// fused window attention: 1 block = 1 window, 4 waves = 4 heads.
// x staged once in LDS; SEPARATE ob buffer (34.8 KB), 2 barriers.
// PV computed TRANSPOSED via operand swap (one bf16x4 LDS write per (tt,dt)).
// bounds(256,3): 170-reg budget (R20: occupancy-insensitive 28-38%).
// ALL QKV weight fragments (96 regs) prefetched before staging — every
// weight-load stall is hidden under staging/B1/earlier phases. proj weights
// prefetched before the attention loop (R21/R22-verified). Attn-bias loads
// stay IN-LOOP: double-buffering them across softmax spills (R18, R23).
// ---------------------------------------------------------------------------
__global__ __launch_bounds__(256, 3)
void wattn_fused(const float* __restrict__ x, const float* __restrict__ qkv_b,
                 const float* __restrict__ proj_b,
                 const __bf16* __restrict__ wq, const __bf16* __restrict__ wp,
                 const float* __restrict__ biasp, const float* __restrict__ mask,
                 const int* __restrict__ mf, float* __restrict__ out) {
  constexpr int XS = 136, OBS = 136;
  __shared__ __align__(16) __bf16 xb[64 * XS];  // 17408 B
  __shared__ __align__(16) __bf16 ob[64 * OBS]; // 17408 B (separate buffer)

  const int tid = threadIdx.x;
  const int w = tid >> 6, lane = tid & 63, lg = lane >> 4, lm = lane & 15;
  const int b = blockIdx.x;
  const f32x4 zero4 = {0.f, 0.f, 0.f, 0.f};

  const bool hasMask =
      (mf[0] | mf[1] | mf[2] | mf[3] | mf[4] | mf[5] | mf[6] | mf[7]) != 0;

  // ---- hoist ALL QKV weights + biases (latency hides under staging/B1) ----
  bf16x8 wfq[2][4], wfk[2][4], wfv[2][4];
  f32x4 qb4[2], kb4[2];
  float vb[2];
#pragma unroll
  for (int dt = 0; dt < 2; ++dt) {
#pragma unroll
    for (int kk = 0; kk < 4; ++kk) {
      wfq[dt][kk] = *(const bf16x8*)(wq + ((size_t)(((2 * w + dt)) * 4 + kk) * 64 + lane) * 8);
      wfk[dt][kk] = *(const bf16x8*)(wq + ((size_t)((8 + 2 * w + dt) * 4 + kk) * 64 + lane) * 8);
      wfv[dt][kk] = *(const bf16x8*)(wq + ((size_t)((16 + 2 * w + dt) * 4 + kk) * 64 + lane) * 8);
    }
    qb4[dt] = *(const f32x4*)(qkv_b + w * 32 + lg * 8 + dt * 4);
#pragma unroll
    for (int j = 0; j < 4; ++j) qb4[dt][j] *= kQScale;
    kb4[dt] = *(const f32x4*)(qkv_b + 128 + w * 32 + lg * 8 + dt * 4);
    vb[dt]  = qkv_b[256 + w * 32 + dt * 16 + lm];
  }

  // ---- stage x -> xb bf16 (rows 49-63 = row 48 replica) ----
  {
    const float* xp = x + (size_t)b * (kN * kC);
#pragma unroll
    for (int i = 0; i < 8; ++i) {
      const int it = tid + i * 256;
      const int row = it >> 5, col = (it & 31) << 2;
      const int sr = row < kN ? row : (kN - 1);
      f32x4 v = *(const f32x4*)(xp + sr * kC + col);
      bf16x4 h;
      h[0] = (__bf16)v[0]; h[1] = (__bf16)v[1]; h[2] = (__bf16)v[2]; h[3] = (__bf16)v[3];
      *(bf16x4*)(xb + row * XS + col) = h;
    }
  }
  __syncthreads();  // B1: xb ready

#define LDAF(tt, kk) (*(const bf16x8*)(xb + ((tt) * 16 + lm) * XS + (kk) * 32 + lg * 8))

  bf16x8 qf[4], kf[4], vf[2][2];

  // ---- Q^T (permuted dims, dt-outer; bias = acc init; weights resident) ----
  {
    uint2 qh[4][2];
#pragma unroll
    for (int dt = 0; dt < 2; ++dt) {
#pragma unroll
      for (int tt = 0; tt < 4; ++tt) {
        f32x4 acc = qb4[dt];
        __builtin_amdgcn_s_setprio(1);
#pragma unroll
        for (int kk = 0; kk < 4; ++kk) acc = MFMA16(wfq[dt][kk], LDAF(tt, kk), acc);
        __builtin_amdgcn_s_setprio(0);
        qh[tt][dt] = pack4(acc);
      }
    }
#pragma unroll
    for (int tt = 0; tt < 4; ++tt) qf[tt] = cat2(qh[tt][0], qh[tt][1]);
  }

  // ---- K^T (permuted dims, dt-outer; bias = acc init; weights resident) ----
  {
    uint2 kh[4][2];
#pragma unroll
    for (int dt = 0; dt < 2; ++dt) {
#pragma unroll
      for (int tt = 0; tt < 4; ++tt) {
        f32x4 acc = kb4[dt];
        __builtin_amdgcn_s_setprio(1);
#pragma unroll
        for (int kk = 0; kk < 4; ++kk) acc = MFMA16(wfk[dt][kk], LDAF(tt, kk), acc);
        __builtin_amdgcn_s_setprio(0);
        kh[tt][dt] = pack4(acc);
      }
    }
#pragma unroll
    for (int kt = 0; kt < 4; ++kt) kf[kt] = cat2(kh[kt][0], kh[kt][1]);
  }

  // ---- V = x Wv (natural order, dt-outer; bias = acc init; weights resident) ----
  {
    uint2 vh[4][2];
#pragma unroll
    for (int dt = 0; dt < 2; ++dt) {
#pragma unroll
      for (int mt = 0; mt < 4; ++mt) {
        f32x4 acc = {vb[dt], vb[dt], vb[dt], vb[dt]};
        __builtin_amdgcn_s_setprio(1);
#pragma unroll
        for (int kk = 0; kk < 4; ++kk) acc = MFMA16(LDAF(mt, kk), wfv[dt][kk], acc);
        __builtin_amdgcn_s_setprio(0);
        vh[mt][dt] = pack4(acc);
      }
    }
#pragma unroll
    for (int ks = 0; ks < 2; ++ks)
#pragma unroll
      for (int dt = 0; dt < 2; ++dt)
        vf[ks][dt] = cat2(vh[ks * 2][dt], vh[ks * 2 + 1][dt]);
  }
  // no barrier: ob is a separate buffer

  // ---- hoist proj weights + bias: attention covers their latency ----
  bf16x8 wpb[2][4];
#pragma unroll
  for (int n = 0; n < 2; ++n)
#pragma unroll
    for (int kk = 0; kk < 4; ++kk)
      wpb[n][kk] = *(const bf16x8*)(wp + (size_t)(((w * 2 + n) * 4 + kk) * 64 + lane) * 8);
  const float pb0 = proj_b[w * 32 + 2 * lm];
  const float pb1 = proj_b[w * 32 + 2 * lm + 1];

  // ---- attention: S^T = K·Q^T (+bias incl. key mask), exp2 softmax, PV^T ----
  const float* bpp = biasp + w * 4096;
  const float* mkp = mask + (size_t)(b & 63) * (kN * kN);

#pragma unroll
  for (int tt = 0; tt < 4; ++tt) {
    const int tok = tt * 16 + lm;
    // issue bias loads first (independent of the MFMAs) -> latency overlap
    f32x4 bm[4];
#pragma unroll
    for (int kt = 0; kt < 4; ++kt)
      bm[kt] = *(const f32x4*)(bpp + (tok << 6) + kt * 16 + lg * 4);
    f32x4 st[4];
    __builtin_amdgcn_s_setprio(1);
#pragma unroll
    for (int kt = 0; kt < 4; ++kt) st[kt] = MFMA16(kf[kt], qf[tt], zero4);
    __builtin_amdgcn_s_setprio(0);
#pragma unroll
    for (int kt = 0; kt < 4; ++kt)
#pragma unroll
      for (int j = 0; j < 4; ++j) st[kt][j] += bm[kt][j];
    if (hasMask) {
      const int tok2 = tok < kN ? tok : (kN - 1);
#pragma unroll
      for (int kt = 0; kt < 4; ++kt)
#pragma unroll
        for (int j = 0; j < 4; ++j) {
          const int key = kt * 16 + lg * 4 + j;
          const int key2 = key < kN ? key : (kN - 1);
          st[kt][j] += mkp[tok2 * kN + key2] * kLog2e;
        }
    }
    // softmax over keys in exp2 domain (keys on (kt,lg,j); token on lm)
    float m = -3e38f;
#pragma unroll
    for (int kt = 0; kt < 4; ++kt)
#pragma unroll
      for (int j = 0; j < 4; ++j) m = fmaxf(m, st[kt][j]);
    m = fmaxf(m, __shfl_xor(m, 16));
    m = fmaxf(m, __shfl_xor(m, 32));
    float sum = 0.f;
#pragma unroll
    for (int kt = 0; kt < 4; ++kt)
#pragma unroll
      for (int j = 0; j < 4; ++j) {
        const float e = exp2f(st[kt][j] - m);
        st[kt][j] = e;
        sum += e;
      }
    sum += __shfl_xor(sum, 16);
    sum += __shfl_xor(sum, 32);
    const float rs = __builtin_amdgcn_rcpf(sum);
    uint2 pst[4];
#pragma unroll
    for (int kt = 0; kt < 4; ++kt) {
      f32x4 t;
#pragma unroll
      for (int j = 0; j < 4; ++j) t[j] = st[kt][j] * rs;
      pst[kt] = pack4(t);
    }
    // bit-shuffled key order: pa/vf agree -> pure lane-local assembly
    bf16x8 pa0 = cat2(pst[0], pst[1]);
    bf16x8 pa1 = cat2(pst[2], pst[3]);
    // PV TRANSPOSED: mfma(vf, pa) = V^T·P^T = O^T[dim][tok]; lane lm = tok,
    // rows lg*4+j = 4 consecutive dims -> one bf16x4 write per (tt,dt)
#pragma unroll
    for (int dt = 0; dt < 2; ++dt) {
      f32x4 o = MFMA16(vf[0][dt], pa0, zero4);
      o = MFMA16(vf[1][dt], pa1, o);
      bf16x4 ho;
#pragma unroll
      for (int j = 0; j < 4; ++j) ho[j] = (__bf16)o[j];
      *(bf16x4*)(ob + (tt * 16 + lm) * OBS + w * 32 + dt * 16 + lg * 4) = ho;
    }
  }

  __syncthreads();  // B2: ob ready

  // ---- proj GEMM: n-interleaved wp -> lane lm owns cols w*32+2lm+{0,1};
  //      float2 stores = full 128B lines per 16-lane group ----
  {
    float* op = out + (size_t)b * (kN * kC);
#pragma unroll
    for (int mt = 0; mt < 4; ++mt) {
      bf16x8 paf[4];
#pragma unroll
      for (int kk = 0; kk < 4; ++kk)
        paf[kk] = *(const bf16x8*)(ob + (mt * 16 + lm) * OBS + kk * 32 + lg * 8);
      f32x4 a0 = zero4, a1 = zero4;
      __builtin_amdgcn_s_setprio(1);
#pragma unroll
      for (int kk = 0; kk < 4; ++kk) {
        a0 = MFMA16(paf[kk], wpb[0][kk], a0);
        a1 = MFMA16(paf[kk], wpb[1][kk], a1);
      }
      __builtin_amdgcn_s_setprio(0);
#pragma unroll
      for (int j = 0; j < 4; ++j) {
        const int r = mt * 16 + lg * 4 + j;
        if (r < kN) {
          float2 st2;
          st2.x = a0[j] + pb0;
          st2.y = a1[j] + pb1;
          *(float2*)(op + r * kC + w * 32 + 2 * lm) = st2;
        }
      }
    }
  }
#undef LDAF
}

// ---------------------------------------------------------------------------
extern "C" void kernel_launch(void* const* d_in, const int* in_sizes, int n_in,
                              void* d_out, int out_size, void* d_ws, size_t ws_size,
                              hipStream_t stream) {
  const float* x          = (const float*)d_in[0];
  const float* mask       = (const float*)d_in[1];
  const float* qkv_w      = (const float*)d_in[2];
  const float* qkv_b      = (const float*)d_in[3];
  const float* proj_w     = (const float*)d_in[4];
  const float* proj_b     = (const float*)d_in[5];
  const float* bias_table = (const float*)d_in[6];
  const int*   rel        = (const int*)d_in[7];

  char* ws = (char*)d_ws;
  __bf16* wq   = (__bf16*)(ws + WQ_OFF);
  __bf16* wp   = (__bf16*)(ws + WP_OFF);
  float* biasp = (float*)(ws + BP_OFF);
  int*   mf    = (int*)(ws + MF_OFF);

  prep_kernel<<<104, 256, 0, stream>>>(qkv_w, proj_w, bias_table, rel, mask,
                                       wq, wp, biasp, mf);
  wattn_fused<<<kB, 256, 0, stream>>>(x, qkv_b, proj_b, wq, wp, biasp, mask,
                                      mf, (float*)d_out);
}